// Round 8
// baseline (267.309 us; speedup 1.0000x reference)
//
#include <hip/hip_runtime.h>
#include <stdint.h>

#define D_MODEL 1024
#define NH      16
#define BB      4
#define TT      2048
#define MROWS   (BB * TT)   // 8192

typedef __attribute__((ext_vector_type(8))) short bf16x8;
typedef __attribute__((ext_vector_type(4))) short bf16x4;
typedef __attribute__((ext_vector_type(4))) float f32x4;

// 16x16x16 bf16 MFMA (carried-forward instruction; builtin name varies by toolchain)
#if defined(__has_builtin)
#if __has_builtin(__builtin_amdgcn_mfma_f32_16x16x16bf16_1k)
#define MFMA16(a, b, c) __builtin_amdgcn_mfma_f32_16x16x16bf16_1k(a, b, c, 0, 0, 0)
#elif __has_builtin(__builtin_amdgcn_mfma_f32_16x16x16_bf16_1k)
#define MFMA16(a, b, c) __builtin_amdgcn_mfma_f32_16x16x16_bf16_1k(a, b, c, 0, 0, 0)
#endif
#endif
#ifndef MFMA16
static __device__ __forceinline__ f32x4 mfma16_asm(bf16x4 a, bf16x4 b, f32x4 c) {
    asm volatile("v_mfma_f32_16x16x16_bf16 %0, %1, %2, %0" : "+v"(c) : "v"(a), "v"(b));
    return c;
}
#define MFMA16(a, b, c) mfma16_asm(a, b, c)
#endif

__device__ __forceinline__ unsigned short f2bf(float f) {
    union { float f; unsigned int u; } v; v.f = f;
    unsigned int r = v.u + 0x7fffu + ((v.u >> 16) & 1u);   // RNE
    return (unsigned short)(r >> 16);
}

__device__ __forceinline__ unsigned int f2bf_fast(float f) {   // round-half-up
    union { float f; unsigned int u; } v; v.f = f;
    return (v.u + 0x8000u) >> 16;
}

__device__ __forceinline__ void gload_lds16(const unsigned short* g, unsigned short* l) {
    __builtin_amdgcn_global_load_lds(
        (const __attribute__((address_space(1))) void*)g,
        (__attribute__((address_space(3))) void*)l,
        16, 0, 0);
}

// ---------------- convert x: fp32 -> bf16 ----------------
__global__ void convert_x_kernel(const float* __restrict__ x, unsigned short* __restrict__ xb) {
    int i = blockIdx.x * 256 + threadIdx.x;     // one float4 per thread
    float4 v = ((const float4*)x)[i];
    ushort4 o;
    o.x = f2bf(v.x); o.y = f2bf(v.y); o.z = f2bf(v.z); o.w = f2bf(v.w);
    ((ushort4*)xb)[i] = o;
}

// ---------------- transpose+convert weights: [K,N] fp32 -> [N,K] bf16 ----------------
__global__ void transpose_w_kernel(const float* __restrict__ wq, const float* __restrict__ wk,
                                   const float* __restrict__ wv, const float* __restrict__ wo,
                                   unsigned short* tq, unsigned short* tk,
                                   unsigned short* tv, unsigned short* to_) {
    const float* src; unsigned short* dst;
    switch (blockIdx.z) {
        case 0:  src = wq; dst = tq; break;
        case 1:  src = wk; dst = tk; break;
        case 2:  src = wv; dst = tv; break;
        default: src = wo; dst = to_; break;
    }
    __shared__ float tile[32][33];
    int tx = threadIdx.x & 31, ty = threadIdx.x >> 5;   // 32 x 8
    int k0 = blockIdx.y * 32, n0 = blockIdx.x * 32;
    #pragma unroll
    for (int i = 0; i < 4; ++i)
        tile[ty + i * 8][tx] = src[(k0 + ty + i * 8) * D_MODEL + n0 + tx];
    __syncthreads();
    #pragma unroll
    for (int i = 0; i < 4; ++i)
        dst[(n0 + ty + i * 8) * D_MODEL + k0 + tx] = f2bf(tile[tx][ty + i * 8]);
}

// ---------------- shared 128x256 GEMM mainloop, BK=64 (A[M,K] * Bt[N,K]^T) ----------------
// 64 MFMAs per barrier-pair (2x the 128x128 tile): halves the relative cost of
// the per-iter vmcnt(0)+barrier drain; fragment-read FLOP/B 341 vs 256.
__device__ __forceinline__ void gemm_mainloop256(const unsigned short* __restrict__ A,
                                                 const unsigned short* __restrict__ Bt,
                                                 int m0, int n0,
                                                 unsigned short* As, unsigned short* Bs,
                                                 f32x4 acc[4][8]) {
    const int tid = threadIdx.x;
    const int lane = tid & 63, wave = tid >> 6;
    const int wm = (wave >> 1) * 64, wn = (wave & 1) * 128;
    const int l15 = lane & 15, quad = lane >> 4;
    const int rx7 = l15 & 7;
    const int srow = tid >> 3;                       // 0..31
    const int scol = ((tid & 7) ^ (srow & 7)) * 8;   // source chunk, XOR-swizzled
    const unsigned short* Ag = A + (size_t)(m0 + srow) * D_MODEL + scol;
    const unsigned short* Bg = Bt + (size_t)(n0 + srow) * D_MODEL + scol;
    unsigned short* AsW = As + wave * 512;           // wave-uniform LDS base
    unsigned short* BsW = Bs + wave * 512;
    for (int k0 = 0; k0 < D_MODEL; k0 += 64) {
        __syncthreads();
        #pragma unroll
        for (int p = 0; p < 4; ++p)                  // A: 128 rows in 4 groups of 32
            gload_lds16(Ag + k0 + (size_t)(32 * p) * D_MODEL, AsW + (32 * p) * 64);
        #pragma unroll
        for (int p = 0; p < 8; ++p)                  // B: 256 rows in 8 groups of 32
            gload_lds16(Bg + k0 + (size_t)(32 * p) * D_MODEL, BsW + (32 * p) * 64);
        __syncthreads();
        #pragma unroll
        for (int kk = 0; kk < 2; ++kk) {
            const int co = ((kk * 4 + quad) ^ rx7) * 8;
            bf16x8 af[4], bfr[8];
            #pragma unroll
            for (int mt = 0; mt < 4; ++mt)
                af[mt] = *(const bf16x8*)(As + (wm + mt * 16 + l15) * 64 + co);
            #pragma unroll
            for (int nt = 0; nt < 8; ++nt)
                bfr[nt] = *(const bf16x8*)(Bs + (wn + nt * 16 + l15) * 64 + co);
            #pragma unroll
            for (int mt = 0; mt < 4; ++mt)
                #pragma unroll
                for (int nt = 0; nt < 8; ++nt)
                    acc[mt][nt] = __builtin_amdgcn_mfma_f32_16x16x32_bf16(af[mt], bfr[nt], acc[mt][nt], 0, 0, 0);
        }
    }
}

// ---------------- fused QKV projection GEMM (N = 3072), 128x256 tiles ----------------
// Wt = [Wq^T | Wk^T | Wv^T] contiguous, [3072][1024] bf16.
// Q,K out: [BH,T,64] bf16 (Q pre-scaled by 0.125*log2e), epilogue restaged via
// LDS (two head-passes) for full-128B-line stores. V out: TILED [BH][16][64][128].
__global__ __launch_bounds__(256, 2) void gemm_qkv_kernel(
        const unsigned short* __restrict__ Xb, const unsigned short* __restrict__ Wt,
        const float* __restrict__ bq, const float* __restrict__ bk, const float* __restrict__ bv,
        unsigned short* __restrict__ Qo, unsigned short* __restrict__ Ko,
        unsigned short* __restrict__ VTo) {
    __shared__ unsigned short S[24576];   // mainloop: As=S[0:8192), Bs=S[8192:24576); epilogue: 2 x 9216 stage
    unsigned short* As = S;
    unsigned short* Bs = S + 8192;
    int m0 = blockIdx.y * 128, n0 = blockIdx.x * 256;
    f32x4 acc[4][8];
    #pragma unroll
    for (int mt = 0; mt < 4; ++mt)
        #pragma unroll
        for (int nt = 0; nt < 8; ++nt)
            acc[mt][nt] = (f32x4){0.f, 0.f, 0.f, 0.f};
    gemm_mainloop256(Xb, Wt, m0, n0, As, Bs, acc);

    const int sel = n0 >> 10;                 // 0=Q 1=K 2=V (uniform per block; 256 | 1024)
    const float* bias = (sel == 0) ? bq : (sel == 1) ? bk : bv;
    const float scale = (sel == 0) ? 0.125f * 1.44269504f : 1.f;
    const int tid = threadIdx.x, lane = tid & 63, wave = tid >> 6;
    const int wm = (wave >> 1) * 64, wn = (wave & 1) * 128, l15 = lane & 15, quad = lane >> 4;
    if (sel < 2) {
        unsigned short* Out = (sel == 0) ? Qo : Ko;
        const int h0 = (n0 & 1023) >> 6;
        const int b = m0 >> 11, tb = m0 & 2047;
        unsigned short* R = S + (wn >> 7) * 9216;   // region per wave-half
        __syncthreads();   // mainloop LDS reads done before repurposing S
        #pragma unroll
        for (int ph = 0; ph < 2; ++ph) {            // two head-passes (2 heads each)
            #pragma unroll
            for (int nt = ph * 4; nt < ph * 4 + 4; ++nt) {
                int col = n0 + wn + nt * 16 + l15;
                float bv_ = bias[col & 1023];
                int ln = (nt & 3) * 16 + l15;
                #pragma unroll
                for (int mt = 0; mt < 4; ++mt)
                    #pragma unroll
                    for (int r = 0; r < 4; ++r) {
                        int lm = wm + mt * 16 + quad * 4 + r;
                        R[lm * 72 + ln] = f2bf((acc[mt][nt][r] + bv_) * scale);
                    }
            }
            __syncthreads();
            {
                int hsel = tid >> 7, t = tid & 127;   // one full 128-B row per thread
                int head = h0 + ph + hsel * 2;
                unsigned short* gp = Out + (size_t)((b * NH + head) * TT + tb + t) * 64;
                const unsigned short* lp = S + hsel * 9216 + t * 72;
                #pragma unroll
                for (int j = 0; j < 8; ++j)
                    *(uint4*)(gp + j * 8) = *(const uint4*)(lp + j * 8);
            }
            if (ph == 0) __syncthreads();
        }
    } else {
        #pragma unroll
        for (int nt = 0; nt < 8; ++nt) {
            int col = (n0 + wn + nt * 16 + l15) & 1023;
            float bv_ = bias[col];
            int h = col >> 6, dd = col & 63;
            #pragma unroll
            for (int mt = 0; mt < 4; ++mt) {
                int gm0 = m0 + wm + mt * 16 + quad * 4;
                int b = gm0 >> 11, t0 = gm0 & 2047;
                ushort4 o;
                o.x = f2bf(acc[mt][nt][0] + bv_);
                o.y = f2bf(acc[mt][nt][1] + bv_);
                o.z = f2bf(acc[mt][nt][2] + bv_);
                o.w = f2bf(acc[mt][nt][3] + bv_);
                // tiled: [BH][tile=t>>7][d][t&127]
                *(ushort4*)&VTo[(((size_t)(b * NH + h) * 16 + (t0 >> 7)) * 64 + dd) * 128 + (t0 & 127)] = o;
            }
        }
    }
}

// ---------------- output projection GEMM: fp32 out + bias, 128x256 tiles ----------------
__global__ __launch_bounds__(256, 2) void gemm_out_kernel(
        const unsigned short* __restrict__ Ob, const unsigned short* __restrict__ Wto,
        const float* __restrict__ bo, float* __restrict__ out) {
    __shared__ unsigned short As[8192], Bs[16384];
    int m0 = blockIdx.y * 128, n0 = blockIdx.x * 256;
    f32x4 acc[4][8];
    #pragma unroll
    for (int mt = 0; mt < 4; ++mt)
        #pragma unroll
        for (int nt = 0; nt < 8; ++nt)
            acc[mt][nt] = (f32x4){0.f, 0.f, 0.f, 0.f};
    gemm_mainloop256(Ob, Wto, m0, n0, As, Bs, acc);
    const int tid = threadIdx.x, lane = tid & 63, wave = tid >> 6;
    const int wm = (wave >> 1) * 64, wn = (wave & 1) * 128, l15 = lane & 15, quad = lane >> 4;
    #pragma unroll
    for (int nt = 0; nt < 8; ++nt) {
        int gn = n0 + wn + nt * 16 + l15;
        float bv_ = bo[gn];
        #pragma unroll
        for (int mt = 0; mt < 4; ++mt) {
            #pragma unroll
            for (int r = 0; r < 4; ++r) {
                int gm = m0 + wm + mt * 16 + quad * 4 + r;
                out[(size_t)gm * D_MODEL + gn] = acc[mt][nt][r] + bv_;
            }
        }
    }
}

// ---------------- causal flash attention (transposed-S, zero P round-trip) ----------------
// Q: [BH,T,64] bf16 pre-scaled by 0.125*log2(e). K: [BH,T,64]. VT: tiled [BH][16][64][128].
// O: [8192, 1024] bf16 (heads merged).
// S^T = K*Q^T (operand swap): C-layout (query=l15, key=quad*4+r) IS the B-operand
// layout of mfma_f32_16x16x16_bf16, so P feeds PV directly from registers:
// O^T = V^T * P^T. No LDS P round-trip, no intra-slice LDS latency chain.
// K/V DMA double-buffered one iteration ahead. LDS 65536 -> 2 blocks/CU.
__global__ __launch_bounds__(256, 2) void flash_kernel(
        const unsigned short* __restrict__ Q, const unsigned short* __restrict__ K,
        const unsigned short* __restrict__ VT, unsigned short* __restrict__ O) {
    __shared__ unsigned short Kd[2][8192];   // K tile dbuf, XOR-swizzled [row][c^(row&7)]
    __shared__ unsigned short Vd[2][8192];   // V^T tile dbuf, XOR-swizzled [d][c^(d&15)]
    const int n = blockIdx.x;
    const int bh = n & 63;                   // head-clustered: all 16 q-tiles of a head on one XCD
    const int qt = 15 - (n >> 6);            // heavy blocks dispatch first
    const int q0 = qt * 128;
    const int tid = threadIdx.x, lane = tid & 63, wave = tid >> 6;
    const int l15 = lane & 15, quad = lane >> 4;
    const int mbase = wave * 32;             // this wave's 32 query rows
    const unsigned short* Qb = Q + (size_t)bh * (TT * 64) + (size_t)q0 * 64;
    const unsigned short* Kb = K + (size_t)bh * (TT * 64);
    const unsigned short* Vtb = VT + (size_t)bh * (16 * 8192);

    // per-lane DMA source offsets (swizzle on the source side; dest is lane-ordered)
    int koff[4], voff[4];
    #pragma unroll
    for (int p = 0; p < 4; ++p) {
        int c = p * 256 + wave * 64 + lane;
        int kr = c >> 3, ks = c & 7;
        koff[p] = kr * 64 + ((ks ^ (kr & 7)) * 8);
        int vd = c >> 4, vs = c & 15;
        voff[p] = vd * 128 + ((vs ^ (vd & 15)) * 8);
    }
    auto fire = [&](int kt, int buf) {
        const unsigned short* Ksrc = Kb + kt * 8192;
        const unsigned short* Vsrc = Vtb + kt * 8192;
        #pragma unroll
        for (int p = 0; p < 4; ++p) {
            gload_lds16(Ksrc + koff[p], &Kd[buf][(p * 256 + wave * 64) * 8]);
            gload_lds16(Vsrc + voff[p], &Vd[buf][(p * 256 + wave * 64) * 8]);
        }
    };

    // Q fragments (B-operand layout: n=query=l15, k=dk=quad*8+j) — registers for whole block
    bf16x8 qf[2][2];
    #pragma unroll
    for (int mt = 0; mt < 2; ++mt)
        #pragma unroll
        for (int kk = 0; kk < 2; ++kk)
            qf[mt][kk] = *(const bf16x8*)(Qb + (size_t)(mbase + mt * 16 + l15) * 64 + kk * 32 + quad * 8);

    float l_part[2] = {0.f, 0.f};            // per-lane partial row-sum (query = l15)
    f32x4 acc[2][4];                         // O^T frags: q=l15, d=ntv*16+quad*4+r
    #pragma unroll
    for (int mt = 0; mt < 2; ++mt)
        #pragma unroll
        for (int nt = 0; nt < 4; ++nt) acc[mt][nt] = (f32x4){0.f, 0.f, 0.f, 0.f};

    fire(0, 0);   // prologue DMA (drained at first barrier)

    for (int kt = 0; kt <= qt; ++kt) {
        const int p = kt & 1;
        __syncthreads();                 // drains DMA(kt) (fired a full iteration ago) + buffer-reuse sync
        if (kt < qt) fire(kt + 1, p ^ 1);
        const unsigned short* Ksl = Kd[p];
        const unsigned short* Vsl = Vd[p];

        #pragma unroll 1
        for (int s2 = 0; s2 < 2; ++s2) {     // 64-key half-tiles
            // S^T = K * Q^T : sf[mt][kt4] C-frags (query=l15, key=quad*4+r)
            f32x4 sf[2][4];
            #pragma unroll
            for (int mt = 0; mt < 2; ++mt)
                #pragma unroll
                for (int k4 = 0; k4 < 4; ++k4) sf[mt][k4] = (f32x4){0.f, 0.f, 0.f, 0.f};
            #pragma unroll
            for (int kk = 0; kk < 2; ++kk)
                #pragma unroll
                for (int k4 = 0; k4 < 4; ++k4) {
                    int row = s2 * 64 + k4 * 16 + l15;
                    bf16x8 kf = *(const bf16x8*)&Ksl[row * 64 + (((kk * 4 + quad) ^ (row & 7)) * 8)];
                    #pragma unroll
                    for (int mt = 0; mt < 2; ++mt)
                        sf[mt][k4] = __builtin_amdgcn_mfma_f32_16x16x32_bf16(kf, qf[mt][kk], sf[mt][k4], 0, 0, 0);
                }
            if (kt == qt) {   // diagonal tile causal mask (exp2(-1e30) -> 0)
                #pragma unroll
                for (int mt = 0; mt < 2; ++mt)
                    #pragma unroll
                    for (int k4 = 0; k4 < 4; ++k4)
                        #pragma unroll
                        for (int r = 0; r < 4; ++r) {
                            int qi = mbase + mt * 16 + l15;
                            int ki = s2 * 64 + k4 * 16 + quad * 4 + r;
                            if (ki > qi) sf[mt][k4][r] = -1e30f;
                        }
            }
            // exp2 + pack P^T B-frags in registers (j element = key quad*4+j = r)
            bf16x4 pf[2][4];
            #pragma unroll
            for (int mt = 0; mt < 2; ++mt)
                #pragma unroll
                for (int k4 = 0; k4 < 4; ++k4) {
                    float e0 = __builtin_amdgcn_exp2f(sf[mt][k4][0]);
                    float e1 = __builtin_amdgcn_exp2f(sf[mt][k4][1]);
                    float e2 = __builtin_amdgcn_exp2f(sf[mt][k4][2]);
                    float e3 = __builtin_amdgcn_exp2f(sf[mt][k4][3]);
                    l_part[mt] += (e0 + e1) + (e2 + e3);
                    union { unsigned int u[2]; bf16x4 v; } pk;
                    pk.u[0] = (f2bf_fast(e1) << 16) | f2bf_fast(e0);
                    pk.u[1] = (f2bf_fast(e3) << 16) | f2bf_fast(e2);
                    pf[mt][k4] = pk.v;
                }
            // O^T += V^T * P^T  (16x16x16: A = V^T frag from LDS b64, B = pf from regs)
            #pragma unroll
            for (int k4 = 0; k4 < 4; ++k4) {
                int kb = s2 * 64 + k4 * 16 + quad * 4;
                int chunk = kb >> 3, within = kb & 7;
                #pragma unroll
                for (int ntv = 0; ntv < 4; ++ntv) {
                    int d = ntv * 16 + l15;
                    bf16x4 va = *(const bf16x4*)&Vsl[d * 128 + ((chunk ^ (d & 15)) * 8) + within];
                    #pragma unroll
                    for (int mt = 0; mt < 2; ++mt)
                        acc[mt][ntv] = MFMA16(va, pf[mt][k4], acc[mt][ntv]);
                }
            }
        }
    }

    // ---- l reduction across the 4 quads (keys partitioned by quad), normalize ----
    const int b = bh >> 4, h = bh & 15;
    float inv[2];
    #pragma unroll
    for (int mt = 0; mt < 2; ++mt) {
        float l = l_part[mt];
        l += __shfl_xor(l, 16);
        l += __shfl_xor(l, 32);
        inv[mt] = __builtin_amdgcn_rcpf(l);
    }
    __syncthreads();   // all waves done with Kd before repurposing as O staging
    unsigned short* Ost = &Kd[0][0];   // 9216 shorts needed, Kd spans 16384
    #pragma unroll
    for (int mt = 0; mt < 2; ++mt)
        #pragma unroll
        for (int ntv = 0; ntv < 4; ++ntv) {
            ushort4 o;
            o.x = f2bf(acc[mt][ntv][0] * inv[mt]);
            o.y = f2bf(acc[mt][ntv][1] * inv[mt]);
            o.z = f2bf(acc[mt][ntv][2] * inv[mt]);
            o.w = f2bf(acc[mt][ntv][3] * inv[mt]);
            // O^T frag: q = l15, d = ntv*16 + quad*4 + r  -> 4 consecutive d = packed store
            *(ushort4*)&Ost[(mbase + mt * 16 + l15) * 72 + ntv * 16 + quad * 4] = o;
        }
    __syncthreads();
    {
        int row = tid >> 1, seg = tid & 1;      // 128 rows x two 32-short segments
        unsigned short* gp = O + (size_t)(b * TT + q0 + row) * D_MODEL + h * 64 + seg * 32;
        const unsigned short* lp = Ost + row * 72 + seg * 32;
        #pragma unroll
        for (int j = 0; j < 4; ++j)
            *(uint4*)(gp + j * 8) = *(const uint4*)(lp + j * 8);
    }
}

extern "C" void kernel_launch(void* const* d_in, const int* in_sizes, int n_in,
                              void* d_out, int out_size, void* d_ws, size_t ws_size,
                              hipStream_t stream) {
    const float* x  = (const float*)d_in[0];
    // d_in[1] = mask (tril causal) — causality applied analytically in flash_kernel
    const float* wq = (const float*)d_in[2];
    const float* bq = (const float*)d_in[3];
    const float* wk = (const float*)d_in[4];
    const float* bk = (const float*)d_in[5];
    const float* wv = (const float*)d_in[6];
    const float* bv = (const float*)d_in[7];
    const float* wo = (const float*)d_in[8];
    const float* bo = (const float*)d_in[9];

    char* ws = (char*)d_ws;
    unsigned short* Xb  = (unsigned short*)ws;                         // 16 MB (reused as flash O)
    unsigned short* Wtq = (unsigned short*)(ws + (size_t)(16 << 20));  // 2 MB each; Q|K|V contiguous
    unsigned short* Wtk = Wtq + (size_t)D_MODEL * D_MODEL;
    unsigned short* Wtv = Wtk + (size_t)D_MODEL * D_MODEL;
    unsigned short* Wto = Wtv + (size_t)D_MODEL * D_MODEL;
    unsigned short* Qb  = Wto + (size_t)D_MODEL * D_MODEL;             // 16 MB each
    unsigned short* Kb  = Qb + (size_t)MROWS * D_MODEL;
    unsigned short* VTb = Kb + (size_t)MROWS * D_MODEL;                // tiled [BH][16][64][128]
    unsigned short* Ob  = Xb;   // alias: X dead after gemm_qkv

    convert_x_kernel<<<(MROWS * D_MODEL) / (256 * 4), 256, 0, stream>>>(x, Xb);
    transpose_w_kernel<<<dim3(32, 32, 4), 256, 0, stream>>>(wq, wk, wv, wo, Wtq, Wtk, Wtv, Wto);
    gemm_qkv_kernel<<<dim3(3 * D_MODEL / 256, MROWS / 128), 256, 0, stream>>>(
        Xb, Wtq, bq, bk, bv, Qb, Kb, VTb);
    flash_kernel<<<dim3(16 * 64), 256, 0, stream>>>(Qb, Kb, VTb, Ob);
    gemm_out_kernel<<<dim3(D_MODEL / 256, MROWS / 128), 256, 0, stream>>>(Ob, Wto, bo, (float*)d_out);
}